// Round 14
// baseline (35.896 us; speedup 1.0000x reference)
//
#include <hip/hip_runtime.h>

#define G_ 1024
#define DIN_ 3072
#define B_ 8192
#define TPB 512
#define UNITS 8            // 2-row units per block -> 16 rows/block
#define NBUF 3             // LDS ring depth (stage-ahead 2)
#define UFLOAT (2 * DIN_)  // floats per unit = 6144 (24 KiB)

// LDS byte offset of a generic pointer that lives in LDS
__device__ __forceinline__ unsigned lds_off(const float* p) {
    return (unsigned)(unsigned long long)(__attribute__((address_space(3))) const float*)p;
}

// ---------------------------------------------------------------------------
// Counted-vmcnt ring pipeline (T3/T4 applied to a streaming gather kernel).
// KNOWN-GOOD R11 (35.8 us, clean compulsory traffic). R12/R13 fine-grained
// variants both failed correctness -- suspected m0-CSE race between
// global_load_lds codegen and the undeclared m0 clobber in our asm; this
// exact code shape is verified on HW. Do not reshape without .s inspection.
//
// Per iteration u (unit = 2 rows, buffer u%3):
//   s_waitcnt vmcnt(N)   N = 3 (u=0) / 6 (u=7) / 9 else  -- NEVER 0:
//       guarantees stage(u) landed while stage(u+1),(u+2) + recent stores fly
//   s_barrier            (raw -- no compiler vmcnt(0) drain)
//   STAGE(u+2)           3x global_load_lds dwordx4 into buf[(u+2)%3]
//   m0 = -1; 12x asm ds_read_b32 gathers; lgkmcnt(0); sched_barrier
//   84 FMA; 6x float2 stores
// Ring safety: stage(u+2) overwrites buf last gathered at iter u-1; gathers
// complete (lgkmcnt 0) before each wave reaches barrier(u) -> WAR safe.
// vmcnt audit robust to compiler store-merging (k=4 or 6 store ops/unit):
// queue entering steady wait = S(u)[3]+st(u-2)[k]+S(u+1)[3]+st(u-1)[k];
// vmcnt(9) drains S(u) for any k >= 3.
// LDS 72 KiB -> 2 blocks/CU; grid 512 = exactly 2/CU, persistent.
// ---------------------------------------------------------------------------
__global__ __launch_bounds__(TPB, 4) void fredkin_pipe_kernel(
    const float* __restrict__ x, const int* __restrict__ conn,
    const float* __restrict__ sel, const float* __restrict__ wg,
    float* __restrict__ out)
{
    __shared__ float xs[NBUF * UFLOAT];   // 72 KiB ring
    const int t = threadIdx.x;
    const int row0 = blockIdx.x * (2 * UNITS);

    // stage unit s (2 rows) into buf s%NBUF: 3 x 16 B per thread, linear dest
    auto STAGE = [&](int s) {
        const float4* src = (const float4*)(x + (size_t)(row0 + 2 * s) * DIN_);
        float4* dst = (float4*)(xs + (s % NBUF) * UFLOAT);
#pragma unroll
        for (int i = 0; i < (UFLOAT / 4) / TPB; ++i)   // 3 iters
            __builtin_amdgcn_global_load_lds(
                (const __attribute__((address_space(1))) void*)(src + t + i * TPB),
                (__attribute__((address_space(3))) void*)(dst + t + i * TPB),
                16, 0, 0);
    };

    STAGE(0);
    asm volatile("" ::: "memory");   // pin issue order (vmcnt FIFO accounting)
    STAGE(1);
    asm volatile("" ::: "memory");

    // ---- coefficient compute for groups 2t, 2t+1 (covers stage flight) ----
    int   cc[2][3];
    float CF[2][3][7];   // per m: K, cx0, cx1, cx2, cq01, cq02, cq12
#pragma unroll
    for (int gi = 0; gi < 2; ++gi) {
        const int g = 2 * t + gi;
        float u_[3], v_[3];
#pragma unroll
        for (int i = 0; i < 3; ++i) {
            cc[gi][i] = conn[g * 3 + i];
            float s = sel[g * 3 + i];
            float C = s / (1.0f + fabsf(s));
            float a = fabsf(C);
            u_[i] = 1.0f - a;
            v_[i] = 0.5f * (C + a);
        }
        float w[6];
        float mx = -1e30f;
#pragma unroll
        for (int p = 0; p < 6; ++p) mx = fmaxf(mx, wg[g * 6 + p]);
        float sum = 0.0f;
#pragma unroll
        for (int p = 0; p < 6; ++p) { w[p] = __expf(wg[g * 6 + p] - mx); sum += w[p]; }
        float inv = 1.0f / sum;
#pragma unroll
        for (int p = 0; p < 6; ++p) w[p] *= inv;

        // itertools.permutations(range(3)); signals:
        // m0 = a ; m1 = c + ab - ac ; m2 = b - ab + ac  (a,b,c = permuted gated)
        const int P[6][3] = {{0,1,2},{0,2,1},{1,0,2},{1,2,0},{2,0,1},{2,1,0}};
        float L[3][3] = {{0.f,0.f,0.f},{0.f,0.f,0.f},{0.f,0.f,0.f}};
        float Q[3][3] = {{0.f,0.f,0.f},{0.f,0.f,0.f},{0.f,0.f,0.f}};
#pragma unroll
        for (int p = 0; p < 6; ++p) {
            int i0 = P[p][0], i1 = P[p][1], i2 = P[p][2];
            float wp = w[p];
            int p01 = i0 + i1 - 1;   // pair idx (i,j)->i+j-1, i<j
            int p02 = i0 + i2 - 1;
            L[0][i0] += wp;
            L[1][i2] += wp; Q[1][p01] += wp; Q[1][p02] -= wp;
            L[2][i1] += wp; Q[2][p01] -= wp; Q[2][p02] += wp;
        }
#pragma unroll
        for (int m = 0; m < 3; ++m) {
            CF[gi][m][0] = L[m][0]*v_[0] + L[m][1]*v_[1] + L[m][2]*v_[2]
                         + Q[m][0]*v_[0]*v_[1] + Q[m][1]*v_[0]*v_[2] + Q[m][2]*v_[1]*v_[2];
            CF[gi][m][1] = u_[0]*(L[m][0] + Q[m][0]*v_[1] + Q[m][1]*v_[2]);
            CF[gi][m][2] = u_[1]*(L[m][1] + Q[m][0]*v_[0] + Q[m][2]*v_[2]);
            CF[gi][m][3] = u_[2]*(L[m][2] + Q[m][1]*v_[0] + Q[m][2]*v_[1]);
            CF[gi][m][4] = Q[m][0]*u_[0]*u_[1];
            CF[gi][m][5] = Q[m][1]*u_[0]*u_[2];
            CF[gi][m][6] = Q[m][2]*u_[1]*u_[2];
        }
    }

    const unsigned xbase = lds_off(xs);

    // ---- main pipeline ----
#pragma unroll
    for (int u = 0; u < UNITS; ++u) {
        // counted wait: stage(u) complete; stage(u+1),(u+2)+stores stay in flight
        if (u == 0)              asm volatile("s_waitcnt vmcnt(3)" ::: "memory");
        else if (u == UNITS - 1) asm volatile("s_waitcnt vmcnt(6)" ::: "memory");
        else                     asm volatile("s_waitcnt vmcnt(9)" ::: "memory");
        __builtin_amdgcn_s_barrier();   // raw: no drain

        if (u + 2 < UNITS) STAGE(u + 2);
        asm volatile("" ::: "memory");

        // gload_lds codegen overwrites m0 (LDS dest base); DS ops use m0 as
        // the LDS limit -> restore before asm gathers.
        asm volatile("s_mov_b32 m0, -1" ::: "memory");

        const unsigned bb = xbase + (unsigned)((u % NBUF) * UFLOAT) * 4u;
        float gv[2][2][3];   // [lr][gi][k], all indices compile-time
#pragma unroll
        for (int lr = 0; lr < 2; ++lr)
#pragma unroll
            for (int gi = 0; gi < 2; ++gi)
#pragma unroll
                for (int k = 0; k < 3; ++k) {
                    unsigned addr = bb + (unsigned)(lr * DIN_ + cc[gi][k]) * 4u;
                    asm volatile("ds_read_b32 %0, %1"
                                 : "=v"(gv[lr][gi][k]) : "v"(addr));
                }
        asm volatile("s_waitcnt lgkmcnt(0)" ::: "memory");
        __builtin_amdgcn_sched_barrier(0);

#pragma unroll
        for (int lr = 0; lr < 2; ++lr) {
            float o[6];
#pragma unroll
            for (int gi = 0; gi < 2; ++gi) {
                const float x0 = gv[lr][gi][0], x1 = gv[lr][gi][1], x2 = gv[lr][gi][2];
                const float p01 = x0 * x1, p02 = x0 * x2, p12 = x1 * x2;
#pragma unroll
                for (int m = 0; m < 3; ++m)
                    o[gi * 3 + m] = CF[gi][m][0]
                                  + CF[gi][m][1]*x0 + CF[gi][m][2]*x1 + CF[gi][m][3]*x2
                                  + CF[gi][m][4]*p01 + CF[gi][m][5]*p02 + CF[gi][m][6]*p12;
            }
            // 24 B contiguous per lane (3 x dwordx2), 6 stores per unit
            float2* op = (float2*)(out + (size_t)(row0 + 2*u + lr) * DIN_ + (size_t)t * 6);
            op[0] = make_float2(o[0], o[1]);
            op[1] = make_float2(o[2], o[3]);
            op[2] = make_float2(o[4], o[5]);
        }
    }
}

extern "C" void kernel_launch(void* const* d_in, const int* in_sizes, int n_in,
                              void* d_out, int out_size, void* d_ws, size_t ws_size,
                              hipStream_t stream) {
    const float* x    = (const float*)d_in[0];
    const int*   conn = (const int*)d_in[1];
    const float* sel  = (const float*)d_in[2];
    const float* wg   = (const float*)d_in[3];
    float* out = (float*)d_out;

    hipLaunchKernelGGL(fredkin_pipe_kernel, dim3(B_ / (2 * UNITS)), dim3(TPB), 0, stream,
                       x, conn, sel, wg, out);
}

// Round 17
// 35.813 us; speedup vs baseline: 1.0023x; 1.0023x over previous
//
#include <hip/hip_runtime.h>

#define G_ 1024
#define DIN_ 3072
#define B_ 8192
#define TPB 512
#define UNITS 8            // 2-row units per block -> 16 rows/block
#define NBUF 3             // LDS ring depth (stage-ahead 2)
#define UFLOAT (2 * DIN_)  // floats per unit = 6144 (24 KiB)

// LDS byte offset of a generic pointer that lives in LDS
__device__ __forceinline__ unsigned lds_off(const float* p) {
    return (unsigned)(unsigned long long)(__attribute__((address_space(3))) const float*)p;
}

// ---------------------------------------------------------------------------
// FINAL: counted-vmcnt ring pipeline, the twice-verified R11/R14 shape
// (35.77 / 35.90 us; FETCH 49.4 MB, WRITE 98.5 MB = compulsory only).
//
// DO NOT RESHAPE. Four structural variants (R12, R13, R15, R16: finer units,
// NBUF=2, different vmcnt counts, m0 save/restore) all failed correctness
// with absmax ~5-12 despite clean source-level audits of the vmcnt FIFO,
// WAR windows, and store-merge robustness. The failure mechanism is below
// source level (most plausibly backend reordering of global_load_lds issue
// order across asm markers, which shifts what vmcnt(N) drains). This exact
// code shape is the one verified on hardware.
//
// out[b,g,m] = K + cx0*x0 + cx1*x1 + cx2*x2 + cq01*x0x1 + cq02*x0x2
//              + cq12*x1x2, x_i = x[b, conn[g,i]]; the 7 coeffs per (g,m)
// fold the soft-gate, the 6 Fredkin permutations, and the softmax weights;
// recomputed in-kernel (covers the prologue stage flight).
//
// Per iteration u (unit = 2 rows, buffer u%3):
//   s_waitcnt vmcnt(N)   N = 3 (u=0) / 6 (u=7) / 9 else  -- NEVER 0:
//       stage(u) landed while stage(u+1),(u+2) + recent stores stay in flight
//   s_barrier            (raw -- no compiler vmcnt(0) drain)
//   STAGE(u+2)           3x global_load_lds dwordx4 into buf[(u+2)%3]
//   m0 = -1; 12x asm ds_read_b32 gathers; lgkmcnt(0); sched_barrier(0)
//   84 FMA; 6x float2 stores
// Ring safety: stage(u+2) overwrites the buffer gathered at iter u-1; all
// waves drained those gathers (lgkmcnt 0) before reaching barrier(u).
// vmcnt audit robust to store-merging (k>=3 store ops/unit): queue at the
// steady wait = S(u)[3]+st(u-2)[k]+S(u+1)[3]+st(u-1)[k]; vmcnt(9) drains
// S(u) for any k >= 3.
// LDS 72 KiB -> 2 blocks/CU; grid 512 = exactly 2/CU. lb(512,4): VGPR 64
// measured, no spill (spilled scratch ops would corrupt the vmcnt counts).
//
// Roofline: 201 MB logical / 35.9 us = 5.6 TB/s combined = 89% of the
// 6.29 TB/s measured copy ceiling; VALU 9%, conflicts ~2% -> memory-bound.
// ---------------------------------------------------------------------------
__global__ __launch_bounds__(TPB, 4) void fredkin_pipe_kernel(
    const float* __restrict__ x, const int* __restrict__ conn,
    const float* __restrict__ sel, const float* __restrict__ wg,
    float* __restrict__ out)
{
    __shared__ float xs[NBUF * UFLOAT];   // 72 KiB ring
    const int t = threadIdx.x;
    const int row0 = blockIdx.x * (2 * UNITS);

    // stage unit s (2 rows) into buf s%NBUF: 3 x 16 B per thread, linear dest
    auto STAGE = [&](int s) {
        const float4* src = (const float4*)(x + (size_t)(row0 + 2 * s) * DIN_);
        float4* dst = (float4*)(xs + (s % NBUF) * UFLOAT);
#pragma unroll
        for (int i = 0; i < (UFLOAT / 4) / TPB; ++i)   // 3 iters
            __builtin_amdgcn_global_load_lds(
                (const __attribute__((address_space(1))) void*)(src + t + i * TPB),
                (__attribute__((address_space(3))) void*)(dst + t + i * TPB),
                16, 0, 0);
    };

    STAGE(0);
    asm volatile("" ::: "memory");   // pin issue order (vmcnt FIFO accounting)
    STAGE(1);
    asm volatile("" ::: "memory");

    // ---- coefficient compute for groups 2t, 2t+1 (covers stage flight) ----
    int   cc[2][3];
    float CF[2][3][7];   // per m: K, cx0, cx1, cx2, cq01, cq02, cq12
#pragma unroll
    for (int gi = 0; gi < 2; ++gi) {
        const int g = 2 * t + gi;
        float u_[3], v_[3];
#pragma unroll
        for (int i = 0; i < 3; ++i) {
            cc[gi][i] = conn[g * 3 + i];
            float s = sel[g * 3 + i];
            float C = s / (1.0f + fabsf(s));
            float a = fabsf(C);
            u_[i] = 1.0f - a;
            v_[i] = 0.5f * (C + a);
        }
        float w[6];
        float mx = -1e30f;
#pragma unroll
        for (int p = 0; p < 6; ++p) mx = fmaxf(mx, wg[g * 6 + p]);
        float sum = 0.0f;
#pragma unroll
        for (int p = 0; p < 6; ++p) { w[p] = __expf(wg[g * 6 + p] - mx); sum += w[p]; }
        float inv = 1.0f / sum;
#pragma unroll
        for (int p = 0; p < 6; ++p) w[p] *= inv;

        // itertools.permutations(range(3)); signals:
        // m0 = a ; m1 = c + ab - ac ; m2 = b - ab + ac  (a,b,c = permuted gated)
        const int P[6][3] = {{0,1,2},{0,2,1},{1,0,2},{1,2,0},{2,0,1},{2,1,0}};
        float L[3][3] = {{0.f,0.f,0.f},{0.f,0.f,0.f},{0.f,0.f,0.f}};
        float Q[3][3] = {{0.f,0.f,0.f},{0.f,0.f,0.f},{0.f,0.f,0.f}};
#pragma unroll
        for (int p = 0; p < 6; ++p) {
            int i0 = P[p][0], i1 = P[p][1], i2 = P[p][2];
            float wp = w[p];
            int p01 = i0 + i1 - 1;   // pair idx (i,j)->i+j-1, i<j
            int p02 = i0 + i2 - 1;
            L[0][i0] += wp;
            L[1][i2] += wp; Q[1][p01] += wp; Q[1][p02] -= wp;
            L[2][i1] += wp; Q[2][p01] -= wp; Q[2][p02] += wp;
        }
#pragma unroll
        for (int m = 0; m < 3; ++m) {
            CF[gi][m][0] = L[m][0]*v_[0] + L[m][1]*v_[1] + L[m][2]*v_[2]
                         + Q[m][0]*v_[0]*v_[1] + Q[m][1]*v_[0]*v_[2] + Q[m][2]*v_[1]*v_[2];
            CF[gi][m][1] = u_[0]*(L[m][0] + Q[m][0]*v_[1] + Q[m][1]*v_[2]);
            CF[gi][m][2] = u_[1]*(L[m][1] + Q[m][0]*v_[0] + Q[m][2]*v_[2]);
            CF[gi][m][3] = u_[2]*(L[m][2] + Q[m][1]*v_[0] + Q[m][2]*v_[1]);
            CF[gi][m][4] = Q[m][0]*u_[0]*u_[1];
            CF[gi][m][5] = Q[m][1]*u_[0]*u_[2];
            CF[gi][m][6] = Q[m][2]*u_[1]*u_[2];
        }
    }

    const unsigned xbase = lds_off(xs);

    // ---- main pipeline ----
#pragma unroll
    for (int u = 0; u < UNITS; ++u) {
        // counted wait: stage(u) complete; stage(u+1),(u+2)+stores stay in flight
        if (u == 0)              asm volatile("s_waitcnt vmcnt(3)" ::: "memory");
        else if (u == UNITS - 1) asm volatile("s_waitcnt vmcnt(6)" ::: "memory");
        else                     asm volatile("s_waitcnt vmcnt(9)" ::: "memory");
        __builtin_amdgcn_s_barrier();   // raw: no drain

        if (u + 2 < UNITS) STAGE(u + 2);
        asm volatile("" ::: "memory");

        // gload_lds codegen overwrites m0 (LDS dest base); DS ops use m0 as
        // the LDS limit -> restore before asm gathers.
        asm volatile("s_mov_b32 m0, -1" ::: "memory");

        const unsigned bb = xbase + (unsigned)((u % NBUF) * UFLOAT) * 4u;
        float gv[2][2][3];   // [lr][gi][k], all indices compile-time
#pragma unroll
        for (int lr = 0; lr < 2; ++lr)
#pragma unroll
            for (int gi = 0; gi < 2; ++gi)
#pragma unroll
                for (int k = 0; k < 3; ++k) {
                    unsigned addr = bb + (unsigned)(lr * DIN_ + cc[gi][k]) * 4u;
                    asm volatile("ds_read_b32 %0, %1"
                                 : "=v"(gv[lr][gi][k]) : "v"(addr));
                }
        asm volatile("s_waitcnt lgkmcnt(0)" ::: "memory");
        __builtin_amdgcn_sched_barrier(0);

#pragma unroll
        for (int lr = 0; lr < 2; ++lr) {
            float o[6];
#pragma unroll
            for (int gi = 0; gi < 2; ++gi) {
                const float x0 = gv[lr][gi][0], x1 = gv[lr][gi][1], x2 = gv[lr][gi][2];
                const float p01 = x0 * x1, p02 = x0 * x2, p12 = x1 * x2;
#pragma unroll
                for (int m = 0; m < 3; ++m)
                    o[gi * 3 + m] = CF[gi][m][0]
                                  + CF[gi][m][1]*x0 + CF[gi][m][2]*x1 + CF[gi][m][3]*x2
                                  + CF[gi][m][4]*p01 + CF[gi][m][5]*p02 + CF[gi][m][6]*p12;
            }
            // 24 B contiguous per lane (3 x dwordx2), 6 stores per unit
            float2* op = (float2*)(out + (size_t)(row0 + 2*u + lr) * DIN_ + (size_t)t * 6);
            op[0] = make_float2(o[0], o[1]);
            op[1] = make_float2(o[2], o[3]);
            op[2] = make_float2(o[4], o[5]);
        }
    }
}

extern "C" void kernel_launch(void* const* d_in, const int* in_sizes, int n_in,
                              void* d_out, int out_size, void* d_ws, size_t ws_size,
                              hipStream_t stream) {
    const float* x    = (const float*)d_in[0];
    const int*   conn = (const int*)d_in[1];
    const float* sel  = (const float*)d_in[2];
    const float* wg   = (const float*)d_in[3];
    float* out = (float*)d_out;

    hipLaunchKernelGGL(fredkin_pipe_kernel, dim3(B_ / (2 * UNITS)), dim3(TPB), 0, stream,
                       x, conn, sel, wg, out);
}